// Round 7
// baseline (231.381 us; speedup 1.0000x reference)
//
#include <hip/hip_runtime.h>

#define S_LEN 4096
#define BATCH 2
#define HID 512
#define HEADS 8
#define HD 64
#define NX (BATCH * S_LEN * HID)       // 4,194,304
#define WSZ (HID * HID)                // 262,144
#define NBH (BATCH * HEADS)            // 16
#define QB 64                          // q rows per attn block
#define NBLK (S_LEN / QB * NBH)        // 1024

typedef short v8s __attribute__((ext_vector_type(8)));    // 8 bf16
typedef float v4f __attribute__((ext_vector_type(4)));    // 16x16 MFMA acc
typedef float v16f __attribute__((ext_vector_type(16)));  // 32x32 MFMA acc
typedef unsigned short ushort_t;

__device__ __forceinline__ ushort_t f2bf(float f) {       // RNE
  unsigned u = __builtin_bit_cast(unsigned, f);
  u += 0x7fffu + ((u >> 16) & 1u);
  return (ushort_t)(u >> 16);
}
__device__ __forceinline__ unsigned pk2(float a, float b) {  // trunc pack
  return (__builtin_bit_cast(unsigned, a) >> 16) |
         (__builtin_bit_cast(unsigned, b) & 0xFFFF0000u);
}
__device__ __forceinline__ float fexp2(float x) {         // native v_exp_f32
  return __builtin_amdgcn_exp2f(x);
}

// fragment-linear Q/K: per head, per 32-row column (col = s>>5):
// off = col*2048 + ((d>>4)*64 + ((d>>3)&1)*32 + (s&31))*8 + (d&7)
// -> a 32x32x16 MFMA A/B frag (row/col = lane&31, k = 8*(lane>>5)+j) is one
//    v8s load at (kstep*64 + lane)*8: 1KB contiguous per wave instruction.

// ---------------------------------------------------------------------------
// Pre-convert fp32 -> bf16: x then Wq,Wk,Wv,Wo contiguous into dst.
// ---------------------------------------------------------------------------
__global__ __launch_bounds__(256) void cvt_k(
    const float* __restrict__ x,
    const float* __restrict__ wq, const float* __restrict__ wk,
    const float* __restrict__ wv, const float* __restrict__ wo,
    ushort_t* __restrict__ dst)
{
  const size_t e = ((size_t)blockIdx.x * 256 + threadIdx.x) * 4;
  const float* src; size_t off;
  if (e < NX) { src = x; off = e; }
  else {
    const size_t we = e - NX;
    const int wi = (int)(we >> 18);
    src = wi == 0 ? wq : wi == 1 ? wk : wi == 2 ? wv : wo;
    off = we & (WSZ - 1);
  }
  float4 v = *(const float4*)&src[off];
  uint2 u; u.x = pk2(v.x, v.y); u.y = pk2(v.z, v.w);
  *(uint2*)&dst[e] = u;
}

// ---------------------------------------------------------------------------
// GEMM (bf16 in): D[m][e] = (sum_d X[m][d]*W[e][d] + bias[e]) * osc
// MODE 1: 3 contiguous weights -> Q,K frag-linear bf16 (Q scaled 0.125*log2e),
//         V plain [B,H,S,HD].
// MODE 2: single weight, fp32 out [M][HID].
// BMxBN tile, BK=32, 4 waves (2x2), 16x16x32 bf16 MFMA.
// ---------------------------------------------------------------------------
template<int BM, int BN, int MODE>
__global__ __launch_bounds__(256) void gemm_k(
    const ushort_t* __restrict__ X, const ushort_t* __restrict__ Wb,
    const float* __restrict__ b0, const float* __restrict__ b1, const float* __restrict__ b2,
    ushort_t* __restrict__ Dq, ushort_t* __restrict__ Dk, ushort_t* __restrict__ Dv,
    float* __restrict__ Df, float qscale)
{
  constexpr int FM = BM / 32, FN = BN / 32;
  __shared__ ushort_t As[BM][40];     // 80B rows -> 2-way bank alias (free)
  __shared__ ushort_t Bs[BN][40];
  const int t = threadIdx.x;
  const int lane = t & 63;
  const int l15 = lane & 15, lg = lane >> 4;
  const int w = t >> 6;
  const int wr = w >> 1, wc = w & 1;
  const int m0 = blockIdx.y * BM;

  int e0, wsel = 0;
  const ushort_t* W;
  const float* bias;
  float osc = 1.0f;
  if (MODE == 1) {
    wsel = blockIdx.x >> 2;                 // 4 n-tiles (BN=128) per weight
    e0 = (blockIdx.x & 3) * BN;
    W = Wb + (size_t)wsel * WSZ;
    bias = wsel == 0 ? b0 : wsel == 1 ? b1 : b2;
    if (wsel == 0) osc = qscale;
  } else {
    e0 = blockIdx.x * BN;
    W = Wb; bias = b0;
  }

  v4f acc[FM][FN] = {};
  const int srow = t >> 2, scol = (t & 3) * 8;

  for (int k0 = 0; k0 < HID; k0 += 32) {
    __syncthreads();
    *(uint4*)&As[srow][scol] =
        *(const uint4*)&X[(size_t)(m0 + srow) * HID + k0 + scol];
    #pragma unroll
    for (int rep = 0; rep < BN / 64; ++rep)
      *(uint4*)&Bs[srow + rep * 64][scol] =
          *(const uint4*)&W[(size_t)(e0 + srow + rep * 64) * HID + k0 + scol];
    __syncthreads();
    v8s a[FM], bf[FN];
    #pragma unroll
    for (int fr = 0; fr < FM; ++fr)
      a[fr] = *(const v8s*)&As[wr * (BM / 2) + 16 * fr + l15][8 * lg];
    #pragma unroll
    for (int fc = 0; fc < FN; ++fc)
      bf[fc] = *(const v8s*)&Bs[wc * (BN / 2) + 16 * fc + l15][8 * lg];
    #pragma unroll
    for (int fr = 0; fr < FM; ++fr)
      #pragma unroll
      for (int fc = 0; fc < FN; ++fc)
        acc[fr][fc] = __builtin_amdgcn_mfma_f32_16x16x32_bf16(a[fr], bf[fc], acc[fr][fc], 0, 0, 0);
  }

  #pragma unroll
  for (int fr = 0; fr < FM; ++fr)
    #pragma unroll
    for (int fc = 0; fc < FN; ++fc) {
      const int e = e0 + wc * (BN / 2) + 16 * fc + l15;
      const float bval = bias[e];
      #pragma unroll
      for (int r = 0; r < 4; ++r) {
        // C/D layout: col = lane&15, row = 4*(lane>>4)+reg  [m89-verified]
        const int m = m0 + wr * (BM / 2) + 16 * fr + 4 * lg + r;
        const float v = (acc[fr][fc][r] + bval) * osc;
        if constexpr (MODE == 1) {
          const int bidx = m >> 12, s = m & (S_LEN - 1);
          const int hh = e >> 6, dh = e & 63;
          const size_t hb = ((size_t)(bidx * HEADS + hh)) * (size_t)(S_LEN * HD);
          if (wsel == 2) {
            Dv[hb + (size_t)s * HD + dh] = f2bf(v);
          } else {
            const size_t off = (size_t)(s >> 5) * 2048 +
                (size_t)(((dh >> 4) * 64 + ((dh >> 3) & 1) * 32 + (s & 31)) * 8 + (dh & 7));
            (wsel == 0 ? Dq : Dk)[hb + off] = f2bf(v);
          }
        } else {
          Df[(size_t)m * HID + e] = v;
        }
      }
    }
}

// ---------------------------------------------------------------------------
// Attention pass 1 (hot): Jensen screen only — per-row running MAX and SUM of
// log2-domain scores, registers only; NO exp2 in the loop. Flag iff
// max - mean > 8.3  (exact cut: 12 - log2(0.1)^-1 ... = 8.678; 0.38 slack,
// conservative direction). L >= 4096*2^mean (Jensen) guarantees no false
// negatives. 512 thr / 8 waves: wave = (rowset rs = w>>2) x (key quarter
// kq = w&3); 32x32x16 MFMA; K frags global->reg (frag-linear, L2-hot).
// State ~90 VGPR -> launch_bounds(512,4), no spills (verify via WRITE_SIZE).
// ---------------------------------------------------------------------------
__global__ __launch_bounds__(512, 4) void attn_p1(
    const ushort_t* __restrict__ Qf, const ushort_t* __restrict__ Kf,
    ushort_t* __restrict__ Cb, int* __restrict__ Flg)
{
  __shared__ float RedM[4][QB];   // [kq][row]
  __shared__ float RedS[4][QB];
  __shared__ int bflag;
  const int t = threadIdx.x;
  const int lane = t & 63;
  const int l31 = lane & 31, hi = lane >> 5;
  const int w = t >> 6;           // 0..7
  const int rs = w >> 2;          // rowset (32 q rows each)
  const int kq = w & 3;           // key quarter
  const int lin = blockIdx.x;
  const int bh = ((lin & 7) << 1) | ((lin >> 3) & 1);   // 2 heads per XCD
  const int q0 = (lin >> 4) * QB;
  if (t == 0) bflag = 0;

  const size_t hoff = (size_t)bh * (size_t)(S_LEN * HD);
  const ushort_t* Qb = Qf + hoff + ((size_t)(q0 >> 5) + rs) * 2048;
  const ushort_t* Kb = Kf + hoff;

  v8s qa[4];
  #pragma unroll
  for (int ks = 0; ks < 4; ++ks)
    qa[ks] = *(const v8s*)&Qb[(ks * 64 + lane) * 8];

  float M[16], S[16];
  #pragma unroll
  for (int j = 0; j < 16; ++j) { M[j] = -1e30f; S[j] = 0.f; }

  for (int i = 0; i < 32; ++i) {
    const ushort_t* kc = Kb + (size_t)(kq + 4 * i) * 2048;
    v8s kb[4];
    #pragma unroll
    for (int ks = 0; ks < 4; ++ks)
      kb[ks] = *(const v8s*)&kc[(ks * 64 + lane) * 8];
    v16f s = {};
    #pragma unroll
    for (int ks = 0; ks < 4; ++ks)
      s = __builtin_amdgcn_mfma_f32_32x32x16_bf16(qa[ks], kb[ks], s, 0, 0, 0);
    #pragma unroll
    for (int j = 0; j < 16; ++j) {
      M[j] = fmaxf(M[j], s[j]);
      S[j] += s[j];
    }
  }

  // reduce across the 32 key-lanes
  #pragma unroll
  for (int j = 0; j < 16; ++j) {
    float Mv = M[j], Sv = S[j];
    Mv = fmaxf(Mv, __shfl_xor(Mv, 1));  Sv += __shfl_xor(Sv, 1);
    Mv = fmaxf(Mv, __shfl_xor(Mv, 2));  Sv += __shfl_xor(Sv, 2);
    Mv = fmaxf(Mv, __shfl_xor(Mv, 4));  Sv += __shfl_xor(Sv, 4);
    Mv = fmaxf(Mv, __shfl_xor(Mv, 8));  Sv += __shfl_xor(Sv, 8);
    Mv = fmaxf(Mv, __shfl_xor(Mv, 16)); Sv += __shfl_xor(Sv, 16);
    if (l31 == 0) {
      // C/D 32x32: row = (reg&3)+8*(reg>>2)+4*(lane>>5)  [m74/m101]
      const int row = rs * 32 + (j & 3) + 8 * (j >> 2) + 4 * hi;
      RedM[kq][row] = Mv; RedS[kq][row] = Sv;
    }
  }
  __syncthreads();
  if (t < QB) {
    const float Mv = fmaxf(fmaxf(RedM[0][t], RedM[1][t]),
                           fmaxf(RedM[2][t], RedM[3][t]));
    const float Sv = RedS[0][t] + RedS[1][t] + RedS[2][t] + RedS[3][t];
    // flag iff 2^M / (4096*2^mean) could exceed 0.1:
    //   M - mean > 12 - 3.3219 = 8.678; slack -> 8.3 (more flags = safe)
    if (Mv - Sv * (1.0f / 4096.0f) > 8.3f) atomicOr(&bflag, 1);
  }
  __syncthreads();
  if (t == 0) Flg[lin] = bflag;

  // ctx = 0 exactly when no element passes (0/(0+eps) = 0)
  const int b = bh >> 3, h = bh & 7;
  const int row = t >> 3, d8 = (t & 7) * 8;
  const uint4 z = {0u, 0u, 0u, 0u};
  *(uint4*)&Cb[((size_t)b * S_LEN + q0 + row) * HID + h * HD + d8] = z;
}

// ---------------------------------------------------------------------------
// Attention pass 2 (cold, flagged blocks only): phase A computes exact
// per-row L = sum 2^s; phase B does exact p>0.1 threshold + renorm + PV.
// Correctness path; perf irrelevant (never taken for this data).
// ---------------------------------------------------------------------------
__global__ __launch_bounds__(256) void attn_p2(
    const ushort_t* __restrict__ Qf, const ushort_t* __restrict__ Kf,
    const ushort_t* __restrict__ V, ushort_t* __restrict__ Cb,
    const int* __restrict__ Flg)
{
  const int lin = blockIdx.x;
  if (Flg[lin] == 0) return;
  __shared__ float Osh[QB][HD + 1];
  __shared__ float Dsh[QB];
  __shared__ float RedA[4][QB];
  __shared__ float iLs[QB];
  __shared__ ushort_t Pp[4][32][40];
  __shared__ ushort_t VT[4][HD][40];
  const int t = threadIdx.x;
  const int lane = t & 63;
  const int l31 = lane & 31, hi = lane >> 5;
  const int w = t >> 6;
  const int bh = ((lin & 7) << 1) | ((lin >> 3) & 1);
  const int q0 = (lin >> 4) * QB;
  const size_t hoff = (size_t)bh * (size_t)(S_LEN * HD);
  const ushort_t* Qb = Qf + hoff + (size_t)(q0 >> 5) * 2048;
  const ushort_t* Kb = Kf + hoff;
  const ushort_t* Vh = V + hoff;

  if (t < QB) Dsh[t] = 0.f;
  for (int idx = t; idx < QB * HD; idx += 256) Osh[idx >> 6][idx & 63] = 0.f;

  v8s qa[4], qB[4];
  #pragma unroll
  for (int ks = 0; ks < 4; ++ks) {
    qa[ks] = *(const v8s*)&Qb[(ks * 64 + lane) * 8];
    qB[ks] = *(const v8s*)&Qb[2048 + (ks * 64 + lane) * 8];
  }

  // ---- phase A: exact L per row ----
  float L0[16], L1[16];
  #pragma unroll
  for (int j = 0; j < 16; ++j) { L0[j] = 0.f; L1[j] = 0.f; }
  for (int i = 0; i < 32; ++i) {
    const ushort_t* kc = Kb + (size_t)(w + 4 * i) * 2048;
    v8s kb[4];
    #pragma unroll
    for (int ks = 0; ks < 4; ++ks)
      kb[ks] = *(const v8s*)&kc[(ks * 64 + lane) * 8];
    v16f sa = {}, sb = {};
    #pragma unroll
    for (int ks = 0; ks < 4; ++ks) {
      sa = __builtin_amdgcn_mfma_f32_32x32x16_bf16(qa[ks], kb[ks], sa, 0, 0, 0);
      sb = __builtin_amdgcn_mfma_f32_32x32x16_bf16(qB[ks], kb[ks], sb, 0, 0, 0);
    }
    #pragma unroll
    for (int j = 0; j < 16; ++j) {
      L0[j] += fexp2(sa[j]);
      L1[j] += fexp2(sb[j]);
    }
  }
  #pragma unroll
  for (int rseti = 0; rseti < 2; ++rseti)
    #pragma unroll
    for (int j = 0; j < 16; ++j) {
      float Lv = (rseti == 0) ? L0[j] : L1[j];
      Lv += __shfl_xor(Lv, 1);  Lv += __shfl_xor(Lv, 2);
      Lv += __shfl_xor(Lv, 4);  Lv += __shfl_xor(Lv, 8);
      Lv += __shfl_xor(Lv, 16);
      if (l31 == 0) {
        const int row = rseti * 32 + (j & 3) + 8 * (j >> 2) + 4 * hi;
        RedA[w][row] = Lv;
      }
    }
  __syncthreads();
  if (t < QB)
    iLs[t] = 1.0f / (RedA[0][t] + RedA[1][t] + RedA[2][t] + RedA[3][t]);
  __syncthreads();

  float il[2][16];
  #pragma unroll
  for (int rseti = 0; rseti < 2; ++rseti)
    #pragma unroll
    for (int j = 0; j < 16; ++j)
      il[rseti][j] = iLs[rseti * 32 + (j & 3) + 8 * (j >> 2) + 4 * hi];

  // ---- phase B: threshold + PV ----
  v16f oA[2] = {}, oB[2] = {};
  float den[2][16] = {};

  for (int i = 0; i < 32; ++i) {
    const int c = w + 4 * i;
    const ushort_t* kc = Kb + (size_t)c * 2048;
    v8s kb[4];
    #pragma unroll
    for (int ks = 0; ks < 4; ++ks)
      kb[ks] = *(const v8s*)&kc[(ks * 64 + lane) * 8];
    v16f sa = {}, sb = {};
    #pragma unroll
    for (int ks = 0; ks < 4; ++ks) {
      sa = __builtin_amdgcn_mfma_f32_32x32x16_bf16(qa[ks], kb[ks], sa, 0, 0, 0);
      sb = __builtin_amdgcn_mfma_f32_32x32x16_bf16(qB[ks], kb[ks], sb, 0, 0, 0);
    }
    { // stage V^T for this key column (per-wave private buffer)
      const ushort_t* vsrc = &Vh[((size_t)c * 32 + l31) * HD + hi * 32];
      #pragma unroll
      for (int qq = 0; qq < 4; ++qq) {
        uint4 vv = *(const uint4*)&vsrc[qq * 8];
        const ushort_t* pv = (const ushort_t*)&vv;
        #pragma unroll
        for (int jj = 0; jj < 8; ++jj)
          VT[w][hi * 32 + qq * 8 + jj][l31] = pv[jj];
      }
    }
    #pragma unroll
    for (int rseti = 0; rseti < 2; ++rseti) {
      #pragma unroll
      for (int j = 0; j < 16; ++j) {
        const float s = (rseti == 0) ? sa[j] : sb[j];
        const int row = (j & 3) + 8 * (j >> 2) + 4 * hi;
        float p = fexp2(s) * il[rseti][j];
        p = (p > 0.1f) ? p : 0.f;
        den[rseti][j] += p;
        Pp[w][row][l31] = f2bf(p);       // P[row][key_local]
      }
      // same-wave LDS RAW: compiler orders via lgkmcnt
      v8s pa0 = *(const v8s*)&Pp[w][l31][8 * hi];
      v8s pa1 = *(const v8s*)&Pp[w][l31][16 + 8 * hi];
      #pragma unroll
      for (int dblk = 0; dblk < 2; ++dblk) {
        v8s vb0 = *(const v8s*)&VT[w][dblk * 32 + l31][8 * hi];
        v8s vb1 = *(const v8s*)&VT[w][dblk * 32 + l31][16 + 8 * hi];
        if (rseti == 0) {
          oA[dblk] = __builtin_amdgcn_mfma_f32_32x32x16_bf16(pa0, vb0, oA[dblk], 0, 0, 0);
          oA[dblk] = __builtin_amdgcn_mfma_f32_32x32x16_bf16(pa1, vb1, oA[dblk], 0, 0, 0);
        } else {
          oB[dblk] = __builtin_amdgcn_mfma_f32_32x32x16_bf16(pa0, vb0, oB[dblk], 0, 0, 0);
          oB[dblk] = __builtin_amdgcn_mfma_f32_32x32x16_bf16(pa1, vb1, oB[dblk], 0, 0, 0);
        }
      }
    }
  }

  #pragma unroll
  for (int rseti = 0; rseti < 2; ++rseti)
    #pragma unroll
    for (int j = 0; j < 16; ++j) {
      float d = den[rseti][j];
      d += __shfl_xor(d, 1); d += __shfl_xor(d, 2); d += __shfl_xor(d, 4);
      d += __shfl_xor(d, 8); d += __shfl_xor(d, 16);
      const int row = rseti * 32 + (j & 3) + 8 * (j >> 2) + 4 * hi;
      if (l31 == 0) atomicAdd(&Dsh[row], d);
    }
  #pragma unroll
  for (int rseti = 0; rseti < 2; ++rseti)
    #pragma unroll
    for (int dblk = 0; dblk < 2; ++dblk)
      #pragma unroll
      for (int j = 0; j < 16; ++j) {
        const int row = rseti * 32 + (j & 3) + 8 * (j >> 2) + 4 * hi;
        const float val = (rseti == 0) ? oA[dblk][j] : oB[dblk][j];
        atomicAdd(&Osh[row][dblk * 32 + l31], val);
      }
  __syncthreads();
  const int b = bh >> 3, h = bh & 7;
  for (int idx = t; idx < QB * HD; idx += 256) {
    const int row = idx >> 6, d = idx & 63;
    const float val = Osh[row][d] / (Dsh[row] + 1e-8f);
    Cb[((size_t)b * S_LEN + q0 + row) * HID + h * HD + d] = f2bf(val);
  }
}

// ---------------------------------------------------------------------------
extern "C" void kernel_launch(void* const* d_in, const int* in_sizes, int n_in,
                              void* d_out, int out_size, void* d_ws, size_t ws_size,
                              hipStream_t stream) {
  const float* x  = (const float*)d_in[0];
  const float* Wq = (const float*)d_in[1];
  const float* bq = (const float*)d_in[2];
  const float* Wk = (const float*)d_in[3];
  const float* bk = (const float*)d_in[4];
  const float* Wv = (const float*)d_in[5];
  const float* bv = (const float*)d_in[6];
  const float* Wo = (const float*)d_in[7];
  const float* bo = (const float*)d_in[8];

  int*      Flg  = (int*)d_ws;                  // [1024]
  ushort_t* xb   = (ushort_t*)(Flg + NBLK);     // bf16 x
  ushort_t* wqb  = xb + NX;                     // 3 QKV weights contiguous
  ushort_t* wob  = wqb + 3 * WSZ;
  ushort_t* Qf   = wob + WSZ;                   // frag-linear
  ushort_t* Kf   = Qf + NX;                     // frag-linear
  ushort_t* Vw   = Kf + NX;                     // plain [B,H,S,HD]
  ushort_t* Cb   = Vw + NX;                     // ctx bf16 [B*S][HID]

  const float qscale = 0.125f * 1.44269504f;    // softmax scale * log2(e)

  cvt_k<<<(NX + 4 * WSZ) / 1024, 256, 0, stream>>>(x, Wq, Wk, Wv, Wo, xb);

  gemm_k<64, 128, 1><<<dim3(12, 128), 256, 0, stream>>>(
      xb, wqb, bq, bk, bv, Qf, Kf, Vw, nullptr, qscale);

  attn_p1<<<NBLK, 512, 0, stream>>>(Qf, Kf, Cb, Flg);
  attn_p2<<<NBLK, 256, 0, stream>>>(Qf, Kf, Vw, Cb, Flg);

  gemm_k<64, 64, 2><<<dim3(8, 128), 256, 0, stream>>>(
      Cb, wob, bo, nullptr, nullptr,
      nullptr, nullptr, nullptr, (float*)d_out, 1.0f);
}

// Round 8
// 133.331 us; speedup vs baseline: 1.7354x; 1.7354x over previous
//
#include <hip/hip_runtime.h>

#define S_LEN 4096
#define BATCH 2
#define HID 512
#define HEADS 8
#define HD 64
#define NX (BATCH * S_LEN * HID)       // 4,194,304
#define WSZ (HID * HID)                // 262,144
#define NBH (BATCH * HEADS)            // 16
#define QB 64                          // q rows per attn block
#define NBLK (S_LEN / QB * NBH)        // 1024

typedef short v8s __attribute__((ext_vector_type(8)));    // 8 bf16
typedef float v4f __attribute__((ext_vector_type(4)));    // 16x16 MFMA acc
typedef float v16f __attribute__((ext_vector_type(16)));  // 32x32 MFMA acc
typedef unsigned short ushort_t;

__device__ __forceinline__ ushort_t f2bf(float f) {       // RNE
  unsigned u = __builtin_bit_cast(unsigned, f);
  u += 0x7fffu + ((u >> 16) & 1u);
  return (ushort_t)(u >> 16);
}
__device__ __forceinline__ unsigned pk2(float a, float b) {  // trunc pack
  return (__builtin_bit_cast(unsigned, a) >> 16) |
         (__builtin_bit_cast(unsigned, b) & 0xFFFF0000u);
}
__device__ __forceinline__ float fexp2(float x) {         // native v_exp_f32
  return __builtin_amdgcn_exp2f(x);
}

// fragment-linear Q/K: per head, per 32-row column (col = s>>5):
// off = col*2048 + ((d>>4)*64 + ((d>>3)&1)*32 + (s&31))*8 + (d&7)
// -> a 32x32x16 MFMA A/B frag (row/col = lane&31, k = 8*(lane>>5)+j) is one
//    v8s load at (kstep*64 + lane)*8: 1KB contiguous per wave instruction.

// ---------------------------------------------------------------------------
// Pre-convert fp32 -> bf16: x then Wq,Wk,Wv,Wo contiguous into dst.
// ---------------------------------------------------------------------------
__global__ __launch_bounds__(256) void cvt_k(
    const float* __restrict__ x,
    const float* __restrict__ wq, const float* __restrict__ wk,
    const float* __restrict__ wv, const float* __restrict__ wo,
    ushort_t* __restrict__ dst)
{
  const size_t e = ((size_t)blockIdx.x * 256 + threadIdx.x) * 4;
  const float* src; size_t off;
  if (e < NX) { src = x; off = e; }
  else {
    const size_t we = e - NX;
    const int wi = (int)(we >> 18);
    src = wi == 0 ? wq : wi == 1 ? wk : wi == 2 ? wv : wo;
    off = we & (WSZ - 1);
  }
  float4 v = *(const float4*)&src[off];
  uint2 u; u.x = pk2(v.x, v.y); u.y = pk2(v.z, v.w);
  *(uint2*)&dst[e] = u;
}

// ---------------------------------------------------------------------------
// GEMM (bf16 in): D[m][e] = (sum_d X[m][d]*W[e][d] + bias[e]) * osc
// MODE 1: 3 contiguous weights -> Q,K frag-linear bf16 (Q scaled 0.125*log2e),
//         V plain [B,H,S,HD].
// MODE 2: single weight, fp32 out [M][HID].
// BMxBN tile, BK=32, 4 waves (2x2), 16x16x32 bf16 MFMA.
// ---------------------------------------------------------------------------
template<int BM, int BN, int MODE>
__global__ __launch_bounds__(256) void gemm_k(
    const ushort_t* __restrict__ X, const ushort_t* __restrict__ Wb,
    const float* __restrict__ b0, const float* __restrict__ b1, const float* __restrict__ b2,
    ushort_t* __restrict__ Dq, ushort_t* __restrict__ Dk, ushort_t* __restrict__ Dv,
    float* __restrict__ Df, float qscale)
{
  constexpr int FM = BM / 32, FN = BN / 32;
  __shared__ ushort_t As[BM][40];     // 80B rows -> 2-way bank alias (free)
  __shared__ ushort_t Bs[BN][40];
  const int t = threadIdx.x;
  const int lane = t & 63;
  const int l15 = lane & 15, lg = lane >> 4;
  const int w = t >> 6;
  const int wr = w >> 1, wc = w & 1;
  const int m0 = blockIdx.y * BM;

  int e0, wsel = 0;
  const ushort_t* W;
  const float* bias;
  float osc = 1.0f;
  if (MODE == 1) {
    wsel = blockIdx.x >> 2;                 // 4 n-tiles (BN=128) per weight
    e0 = (blockIdx.x & 3) * BN;
    W = Wb + (size_t)wsel * WSZ;
    bias = wsel == 0 ? b0 : wsel == 1 ? b1 : b2;
    if (wsel == 0) osc = qscale;
  } else {
    e0 = blockIdx.x * BN;
    W = Wb; bias = b0;
  }

  v4f acc[FM][FN] = {};
  const int srow = t >> 2, scol = (t & 3) * 8;

  for (int k0 = 0; k0 < HID; k0 += 32) {
    __syncthreads();
    *(uint4*)&As[srow][scol] =
        *(const uint4*)&X[(size_t)(m0 + srow) * HID + k0 + scol];
    #pragma unroll
    for (int rep = 0; rep < BN / 64; ++rep)
      *(uint4*)&Bs[srow + rep * 64][scol] =
          *(const uint4*)&W[(size_t)(e0 + srow + rep * 64) * HID + k0 + scol];
    __syncthreads();
    v8s a[FM], bf[FN];
    #pragma unroll
    for (int fr = 0; fr < FM; ++fr)
      a[fr] = *(const v8s*)&As[wr * (BM / 2) + 16 * fr + l15][8 * lg];
    #pragma unroll
    for (int fc = 0; fc < FN; ++fc)
      bf[fc] = *(const v8s*)&Bs[wc * (BN / 2) + 16 * fc + l15][8 * lg];
    #pragma unroll
    for (int fr = 0; fr < FM; ++fr)
      #pragma unroll
      for (int fc = 0; fc < FN; ++fc)
        acc[fr][fc] = __builtin_amdgcn_mfma_f32_16x16x32_bf16(a[fr], bf[fc], acc[fr][fc], 0, 0, 0);
  }

  #pragma unroll
  for (int fr = 0; fr < FM; ++fr)
    #pragma unroll
    for (int fc = 0; fc < FN; ++fc) {
      const int e = e0 + wc * (BN / 2) + 16 * fc + l15;
      const float bval = bias[e];
      #pragma unroll
      for (int r = 0; r < 4; ++r) {
        // C/D layout: col = lane&15, row = 4*(lane>>4)+reg  [m89-verified]
        const int m = m0 + wr * (BM / 2) + 16 * fr + 4 * lg + r;
        const float v = (acc[fr][fc][r] + bval) * osc;
        if constexpr (MODE == 1) {
          const int bidx = m >> 12, s = m & (S_LEN - 1);
          const int hh = e >> 6, dh = e & 63;
          const size_t hb = ((size_t)(bidx * HEADS + hh)) * (size_t)(S_LEN * HD);
          if (wsel == 2) {
            Dv[hb + (size_t)s * HD + dh] = f2bf(v);
          } else {
            const size_t off = (size_t)(s >> 5) * 2048 +
                (size_t)(((dh >> 4) * 64 + ((dh >> 3) & 1) * 32 + (s & 31)) * 8 + (dh & 7));
            (wsel == 0 ? Dq : Dk)[hb + off] = f2bf(v);
          }
        } else {
          Df[(size_t)m * HID + e] = v;
        }
      }
    }
}

// ---------------------------------------------------------------------------
// Attention pass 1 (hot): EXACT screen — per-row running MAX and exact
// L = sum 2^s (native v_exp_f32), registers only. Flag iff
// M >= log2(L) - 3.3219 - 0.05  (bf16 slack, conservative). Typical data:
// M ~ 5.1, cut ~ 9.4 -> fires with prob ~1e-7 (R6 verified: never).
// 512 thr / 8 waves: wave = (rowset rs = w>>2) x (key quarter kq = w&3);
// 32x32x16 MFMA; K frags global->reg (frag-linear, L2-hot).
// State: M[16]+L[16]+qa[16]+kb[16]+s(AGPR16) -> fits launch_bounds(512,4).
// ---------------------------------------------------------------------------
__global__ __launch_bounds__(512, 4) void attn_p1(
    const ushort_t* __restrict__ Qf, const ushort_t* __restrict__ Kf,
    ushort_t* __restrict__ Cb, int* __restrict__ Flg)
{
  __shared__ float RedM[4][QB];   // [kq][row]
  __shared__ float RedL[4][QB];
  __shared__ int bflag;
  const int t = threadIdx.x;
  const int lane = t & 63;
  const int l31 = lane & 31, hi = lane >> 5;
  const int w = t >> 6;           // 0..7
  const int rs = w >> 2;          // rowset (32 q rows each)
  const int kq = w & 3;           // key quarter
  const int lin = blockIdx.x;
  const int bh = ((lin & 7) << 1) | ((lin >> 3) & 1);   // 2 heads per XCD
  const int q0 = (lin >> 4) * QB;
  if (t == 0) bflag = 0;

  const size_t hoff = (size_t)bh * (size_t)(S_LEN * HD);
  const ushort_t* Qb = Qf + hoff + ((size_t)(q0 >> 5) + rs) * 2048;
  const ushort_t* Kb = Kf + hoff;

  v8s qa[4];
  #pragma unroll
  for (int ks = 0; ks < 4; ++ks)
    qa[ks] = *(const v8s*)&Qb[(ks * 64 + lane) * 8];

  float M[16], L[16];
  #pragma unroll
  for (int j = 0; j < 16; ++j) { M[j] = -1e30f; L[j] = 0.f; }

  for (int i = 0; i < 32; ++i) {
    const ushort_t* kc = Kb + (size_t)(kq + 4 * i) * 2048;
    v8s kb[4];
    #pragma unroll
    for (int ks = 0; ks < 4; ++ks)
      kb[ks] = *(const v8s*)&kc[(ks * 64 + lane) * 8];
    v16f s = {};
    #pragma unroll
    for (int ks = 0; ks < 4; ++ks)
      s = __builtin_amdgcn_mfma_f32_32x32x16_bf16(qa[ks], kb[ks], s, 0, 0, 0);
    #pragma unroll
    for (int j = 0; j < 16; ++j) {
      M[j] = fmaxf(M[j], s[j]);
      L[j] += fexp2(s[j]);
    }
  }

  // reduce across the 32 key-lanes
  #pragma unroll
  for (int j = 0; j < 16; ++j) {
    float Mv = M[j], Lv = L[j];
    Mv = fmaxf(Mv, __shfl_xor(Mv, 1));  Lv += __shfl_xor(Lv, 1);
    Mv = fmaxf(Mv, __shfl_xor(Mv, 2));  Lv += __shfl_xor(Lv, 2);
    Mv = fmaxf(Mv, __shfl_xor(Mv, 4));  Lv += __shfl_xor(Lv, 4);
    Mv = fmaxf(Mv, __shfl_xor(Mv, 8));  Lv += __shfl_xor(Lv, 8);
    Mv = fmaxf(Mv, __shfl_xor(Mv, 16)); Lv += __shfl_xor(Lv, 16);
    if (l31 == 0) {
      // C/D 32x32: row = (reg&3)+8*(reg>>2)+4*(lane>>5)  [m74/m101]
      const int row = rs * 32 + (j & 3) + 8 * (j >> 2) + 4 * hi;
      RedM[kq][row] = Mv; RedL[kq][row] = Lv;
    }
  }
  __syncthreads();
  if (t < QB) {
    const float Mv = fmaxf(fmaxf(RedM[0][t], RedM[1][t]),
                           fmaxf(RedM[2][t], RedM[3][t]));
    const float Lv = RedL[0][t] + RedL[1][t] + RedL[2][t] + RedL[3][t];
    // exact screen: p>0.1 possible iff M >= log2(L)+log2(0.1); 0.05 slack
    if (Mv >= __log2f(Lv) - 3.3719281f) atomicOr(&bflag, 1);
  }
  __syncthreads();
  if (t == 0) Flg[lin] = bflag;

  // ctx = 0 exactly when no element passes (0/(0+eps) = 0)
  const int b = bh >> 3, h = bh & 7;
  const int row = t >> 3, d8 = (t & 7) * 8;
  const uint4 z = {0u, 0u, 0u, 0u};
  *(uint4*)&Cb[((size_t)b * S_LEN + q0 + row) * HID + h * HD + d8] = z;
}

// ---------------------------------------------------------------------------
// Attention pass 2 (cold, flagged blocks only): phase A computes exact
// per-row L = sum 2^s; phase B does exact p>0.1 threshold + renorm + PV.
// Correctness path; perf irrelevant (never taken for this data).
// ---------------------------------------------------------------------------
__global__ __launch_bounds__(256) void attn_p2(
    const ushort_t* __restrict__ Qf, const ushort_t* __restrict__ Kf,
    const ushort_t* __restrict__ V, ushort_t* __restrict__ Cb,
    const int* __restrict__ Flg)
{
  const int lin = blockIdx.x;
  if (Flg[lin] == 0) return;
  __shared__ float Osh[QB][HD + 1];
  __shared__ float Dsh[QB];
  __shared__ float RedA[4][QB];
  __shared__ float iLs[QB];
  __shared__ ushort_t Pp[4][32][40];
  __shared__ ushort_t VT[4][HD][40];
  const int t = threadIdx.x;
  const int lane = t & 63;
  const int l31 = lane & 31, hi = lane >> 5;
  const int w = t >> 6;
  const int bh = ((lin & 7) << 1) | ((lin >> 3) & 1);
  const int q0 = (lin >> 4) * QB;
  const size_t hoff = (size_t)bh * (size_t)(S_LEN * HD);
  const ushort_t* Qb = Qf + hoff + (size_t)(q0 >> 5) * 2048;
  const ushort_t* Kb = Kf + hoff;
  const ushort_t* Vh = V + hoff;

  if (t < QB) Dsh[t] = 0.f;
  for (int idx = t; idx < QB * HD; idx += 256) Osh[idx >> 6][idx & 63] = 0.f;

  v8s qa[4], qB[4];
  #pragma unroll
  for (int ks = 0; ks < 4; ++ks) {
    qa[ks] = *(const v8s*)&Qb[(ks * 64 + lane) * 8];
    qB[ks] = *(const v8s*)&Qb[2048 + (ks * 64 + lane) * 8];
  }

  // ---- phase A: exact L per row ----
  float L0[16], L1[16];
  #pragma unroll
  for (int j = 0; j < 16; ++j) { L0[j] = 0.f; L1[j] = 0.f; }
  for (int i = 0; i < 32; ++i) {
    const ushort_t* kc = Kb + (size_t)(w + 4 * i) * 2048;
    v8s kb[4];
    #pragma unroll
    for (int ks = 0; ks < 4; ++ks)
      kb[ks] = *(const v8s*)&kc[(ks * 64 + lane) * 8];
    v16f sa = {}, sb = {};
    #pragma unroll
    for (int ks = 0; ks < 4; ++ks) {
      sa = __builtin_amdgcn_mfma_f32_32x32x16_bf16(qa[ks], kb[ks], sa, 0, 0, 0);
      sb = __builtin_amdgcn_mfma_f32_32x32x16_bf16(qB[ks], kb[ks], sb, 0, 0, 0);
    }
    #pragma unroll
    for (int j = 0; j < 16; ++j) {
      L0[j] += fexp2(sa[j]);
      L1[j] += fexp2(sb[j]);
    }
  }
  #pragma unroll
  for (int rseti = 0; rseti < 2; ++rseti)
    #pragma unroll
    for (int j = 0; j < 16; ++j) {
      float Lv = (rseti == 0) ? L0[j] : L1[j];
      Lv += __shfl_xor(Lv, 1);  Lv += __shfl_xor(Lv, 2);
      Lv += __shfl_xor(Lv, 4);  Lv += __shfl_xor(Lv, 8);
      Lv += __shfl_xor(Lv, 16);
      if (l31 == 0) {
        const int row = rseti * 32 + (j & 3) + 8 * (j >> 2) + 4 * hi;
        RedA[w][row] = Lv;
      }
    }
  __syncthreads();
  if (t < QB)
    iLs[t] = 1.0f / (RedA[0][t] + RedA[1][t] + RedA[2][t] + RedA[3][t]);
  __syncthreads();

  float il[2][16];
  #pragma unroll
  for (int rseti = 0; rseti < 2; ++rseti)
    #pragma unroll
    for (int j = 0; j < 16; ++j)
      il[rseti][j] = iLs[rseti * 32 + (j & 3) + 8 * (j >> 2) + 4 * hi];

  // ---- phase B: threshold + PV ----
  v16f oA[2] = {}, oB[2] = {};
  float den[2][16] = {};

  for (int i = 0; i < 32; ++i) {
    const int c = w + 4 * i;
    const ushort_t* kc = Kb + (size_t)c * 2048;
    v8s kb[4];
    #pragma unroll
    for (int ks = 0; ks < 4; ++ks)
      kb[ks] = *(const v8s*)&kc[(ks * 64 + lane) * 8];
    v16f sa = {}, sb = {};
    #pragma unroll
    for (int ks = 0; ks < 4; ++ks) {
      sa = __builtin_amdgcn_mfma_f32_32x32x16_bf16(qa[ks], kb[ks], sa, 0, 0, 0);
      sb = __builtin_amdgcn_mfma_f32_32x32x16_bf16(qB[ks], kb[ks], sb, 0, 0, 0);
    }
    { // stage V^T for this key column (per-wave private buffer)
      const ushort_t* vsrc = &Vh[((size_t)c * 32 + l31) * HD + hi * 32];
      #pragma unroll
      for (int qq = 0; qq < 4; ++qq) {
        uint4 vv = *(const uint4*)&vsrc[qq * 8];
        const ushort_t* pv = (const ushort_t*)&vv;
        #pragma unroll
        for (int jj = 0; jj < 8; ++jj)
          VT[w][hi * 32 + qq * 8 + jj][l31] = pv[jj];
      }
    }
    #pragma unroll
    for (int rseti = 0; rseti < 2; ++rseti) {
      #pragma unroll
      for (int j = 0; j < 16; ++j) {
        const float s = (rseti == 0) ? sa[j] : sb[j];
        const int row = (j & 3) + 8 * (j >> 2) + 4 * hi;
        float p = fexp2(s) * il[rseti][j];
        p = (p > 0.1f) ? p : 0.f;
        den[rseti][j] += p;
        Pp[w][row][l31] = f2bf(p);       // P[row][key_local]
      }
      // same-wave LDS RAW: compiler orders via lgkmcnt
      v8s pa0 = *(const v8s*)&Pp[w][l31][8 * hi];
      v8s pa1 = *(const v8s*)&Pp[w][l31][16 + 8 * hi];
      #pragma unroll
      for (int dblk = 0; dblk < 2; ++dblk) {
        v8s vb0 = *(const v8s*)&VT[w][dblk * 32 + l31][8 * hi];
        v8s vb1 = *(const v8s*)&VT[w][dblk * 32 + l31][16 + 8 * hi];
        if (rseti == 0) {
          oA[dblk] = __builtin_amdgcn_mfma_f32_32x32x16_bf16(pa0, vb0, oA[dblk], 0, 0, 0);
          oA[dblk] = __builtin_amdgcn_mfma_f32_32x32x16_bf16(pa1, vb1, oA[dblk], 0, 0, 0);
        } else {
          oB[dblk] = __builtin_amdgcn_mfma_f32_32x32x16_bf16(pa0, vb0, oB[dblk], 0, 0, 0);
          oB[dblk] = __builtin_amdgcn_mfma_f32_32x32x16_bf16(pa1, vb1, oB[dblk], 0, 0, 0);
        }
      }
    }
  }

  #pragma unroll
  for (int rseti = 0; rseti < 2; ++rseti)
    #pragma unroll
    for (int j = 0; j < 16; ++j) {
      float d = den[rseti][j];
      d += __shfl_xor(d, 1); d += __shfl_xor(d, 2); d += __shfl_xor(d, 4);
      d += __shfl_xor(d, 8); d += __shfl_xor(d, 16);
      const int row = rseti * 32 + (j & 3) + 8 * (j >> 2) + 4 * hi;
      if (l31 == 0) atomicAdd(&Dsh[row], d);
    }
  #pragma unroll
  for (int rseti = 0; rseti < 2; ++rseti)
    #pragma unroll
    for (int dblk = 0; dblk < 2; ++dblk)
      #pragma unroll
      for (int j = 0; j < 16; ++j) {
        const int row = rseti * 32 + (j & 3) + 8 * (j >> 2) + 4 * hi;
        const float val = (rseti == 0) ? oA[dblk][j] : oB[dblk][j];
        atomicAdd(&Osh[row][dblk * 32 + l31], val);
      }
  __syncthreads();
  const int b = bh >> 3, h = bh & 7;
  for (int idx = t; idx < QB * HD; idx += 256) {
    const int row = idx >> 6, d = idx & 63;
    const float val = Osh[row][d] / (Dsh[row] + 1e-8f);
    Cb[((size_t)b * S_LEN + q0 + row) * HID + h * HD + d] = f2bf(val);
  }
}

// ---------------------------------------------------------------------------
extern "C" void kernel_launch(void* const* d_in, const int* in_sizes, int n_in,
                              void* d_out, int out_size, void* d_ws, size_t ws_size,
                              hipStream_t stream) {
  const float* x  = (const float*)d_in[0];
  const float* Wq = (const float*)d_in[1];
  const float* bq = (const float*)d_in[2];
  const float* Wk = (const float*)d_in[3];
  const float* bk = (const float*)d_in[4];
  const float* Wv = (const float*)d_in[5];
  const float* bv = (const float*)d_in[6];
  const float* Wo = (const float*)d_in[7];
  const float* bo = (const float*)d_in[8];

  int*      Flg  = (int*)d_ws;                  // [1024]
  ushort_t* xb   = (ushort_t*)(Flg + NBLK);     // bf16 x
  ushort_t* wqb  = xb + NX;                     // 3 QKV weights contiguous
  ushort_t* wob  = wqb + 3 * WSZ;
  ushort_t* Qf   = wob + WSZ;                   // frag-linear
  ushort_t* Kf   = Qf + NX;                     // frag-linear
  ushort_t* Vw   = Kf + NX;                     // plain [B,H,S,HD]
  ushort_t* Cb   = Vw + NX;                     // ctx bf16 [B*S][HID]

  const float qscale = 0.125f * 1.44269504f;    // softmax scale * log2(e)

  cvt_k<<<(NX + 4 * WSZ) / 1024, 256, 0, stream>>>(x, Wq, Wk, Wv, Wo, xb);

  gemm_k<64, 128, 1><<<dim3(12, 128), 256, 0, stream>>>(
      xb, wqb, bq, bk, bv, Qf, Kf, Vw, nullptr, qscale);

  attn_p1<<<NBLK, 512, 0, stream>>>(Qf, Kf, Cb, Flg);
  attn_p2<<<NBLK, 256, 0, stream>>>(Qf, Kf, Vw, Cb, Flg);

  gemm_k<64, 64, 2><<<dim3(8, 128), 256, 0, stream>>>(
      Cb, wob, bo, nullptr, nullptr,
      nullptr, nullptr, nullptr, (float*)d_out, 1.0f);
}